// Round 5
// baseline (732.138 us; speedup 1.0000x reference)
//
#include <hip/hip_runtime.h>

#define NN 50000
#define EE 800000
#define ET 850000   // EE + NN self loops
#define HH 4
#define CC 64
#define FDIM 256    // HH*CC

#define SCAN_BLK 512
#define SCAN_NB ((NN + SCAN_BLK - 1) / SCAN_BLK)   // 98

typedef unsigned short ushort;
typedef __bf16 bf16x8 __attribute__((ext_vector_type(8)));
typedef float floatx4 __attribute__((ext_vector_type(4)));
typedef ushort ushort8v __attribute__((ext_vector_type(8)));
struct ushort4s { ushort x, y, z, w; };

__device__ __forceinline__ ushort f2bf(float f) {
  union { float f; unsigned u; } v; v.f = f;
  unsigned r = v.u + 0x7fffu + ((v.u >> 16) & 1u);  // RNE
  return (ushort)(r >> 16);
}
__device__ __forceinline__ float bf2f(ushort u) {
  return __uint_as_float(((unsigned)u) << 16);
}

// ---------- edge-index dtype handling (is64 decided HOST-side from in_sizes) ----------
__device__ __forceinline__ int get_edge(const void* p, int is64, long long idx) {
  if (is64) return (int)((const long long*)p)[idx];
  return ((const int*)p)[idx];
}

// ---------- CSR build over dst ----------
__global__ void degree_kernel(const void* eidx, int is64, int* deg) {
  int k = blockIdx.x * blockDim.x + threadIdx.x;
  if (k >= ET) return;
  int dst = (k < EE) ? get_edge(eidx, is64, (long long)EE + k) : (k - EE);
  atomicAdd(&deg[dst], 1);
}

__global__ __launch_bounds__(SCAN_BLK) void scan1_kernel(const int* __restrict__ deg,
                                                         int* __restrict__ rowptr,
                                                         int* __restrict__ bsum) {
  __shared__ int sm[SCAN_BLK];
  int t = threadIdx.x;
  int i = blockIdx.x * SCAN_BLK + t;
  int v = (i < NN) ? deg[i] : 0;
  sm[t] = v;
  __syncthreads();
#pragma unroll
  for (int o = 1; o < SCAN_BLK; o <<= 1) {
    int u = (t >= o) ? sm[t - o] : 0;
    __syncthreads();
    sm[t] += u;
    __syncthreads();
  }
  if (i < NN) rowptr[i] = sm[t] - v;                 // local exclusive
  if (t == SCAN_BLK - 1) bsum[blockIdx.x] = sm[t];   // block total
}

__global__ __launch_bounds__(128) void scan2_kernel(const int* __restrict__ bsum,
                                                    int* __restrict__ boff,
                                                    int* __restrict__ rowptr) {
  __shared__ int sm[128];
  int t = threadIdx.x;
  int v = (t < SCAN_NB) ? bsum[t] : 0;
  sm[t] = v;
  __syncthreads();
#pragma unroll
  for (int o = 1; o < 128; o <<= 1) {
    int u = (t >= o) ? sm[t - o] : 0;
    __syncthreads();
    sm[t] += u;
    __syncthreads();
  }
  if (t < SCAN_NB) boff[t] = sm[t] - v;  // exclusive block offset
  if (t == 0) rowptr[NN] = ET;
}

__global__ __launch_bounds__(SCAN_BLK) void scan3_kernel(int* __restrict__ rowptr,
                                                         int* __restrict__ cursor,
                                                         const int* __restrict__ boff) {
  int i = blockIdx.x * SCAN_BLK + threadIdx.x;
  if (i >= NN) return;
  int v = rowptr[i] + boff[blockIdx.x];
  rowptr[i] = v;
  cursor[i] = v;
}

__global__ void fill_kernel(const void* eidx, int is64, int* cursor, int* csr_src) {
  int k = blockIdx.x * blockDim.x + threadIdx.x;
  if (k >= ET) return;
  int src, dst;
  if (k < EE) {
    src = get_edge(eidx, is64, k);
    dst = get_edge(eidx, is64, (long long)EE + k);
  } else {
    src = dst = k - EE;
  }
  int pos = atomicAdd(&cursor[dst], 1);
  csr_src[pos] = src;
}

// all three weight transposes in one dispatch (grid.y selects the matrix)
__global__ void conv_w_kernel(const float* __restrict__ W0, const float* __restrict__ W1,
                              const float* __restrict__ W2,
                              ushort* __restrict__ T0, ushort* __restrict__ T1,
                              ushort* __restrict__ T2) {
  const float* W = (blockIdx.y == 0) ? W0 : (blockIdx.y == 1) ? W1 : W2;
  ushort* Wt = (blockIdx.y == 0) ? T0 : (blockIdx.y == 1) ? T1 : T2;
  int idx = blockIdx.x * 256 + threadIdx.x;  // 65536
  int k = idx >> 8, n = idx & 255;
  Wt[n * 256 + k] = f2bf(W[idx]);  // transpose: Wt[n][k]
}

// ---------- bf16 MFMA GEMM: BARRIER-FREE, LDS-FREE (R5) ----------
// C[M,256] = A[M,256] @ B[256,256] (B given transposed as Bt[n][k]).
// Theory: old LDS path was barrier-bound (2 barriers x 8 K-steps, small tiles,
// historical MfmaUtil 4-15%). mfma_16x16x32 A/B frags are per-lane CONTIGUOUS
// 16B reads of row-major A / Bt (lane l: row +=(l&15), k += (l>>4)*8) -> load
// frags DIRECTLY to registers. B (128KB) is L2-resident; 4 waves re-read the
// same A rows via L1/L2 (HBM A-traffic stays 1x). Zero barriers in K-loop ->
// compiler pipelines loads/MFMA with vmcnt. Frag addressing identical to the
// proven LDS path -> bit-identical numerics.
// Block = 32 rows x 256 cols, 4 waves, wave w = cols w*64..+64 (2x4 subtiles).
// MODE 0: A f32 (layer 0), inline cvt. MODE 1: A bf16, GraphNorm+LeakyReLU
// fused via scs/shs LDS table (float4 reads, k 8-aligned).
template <int MODE>
__global__ __launch_bounds__(256) void gemm_bf16(const void* __restrict__ Ap,
                                                 const ushort* __restrict__ Bt,
                                                 ushort* __restrict__ C,
                                                 const float* __restrict__ as_,
                                                 const float* __restrict__ ad_,
                                                 float* __restrict__ s_arr,
                                                 float* __restrict__ d_arr,
                                                 const float* __restrict__ colsum,
                                                 const float* __restrict__ colsumsq,
                                                 const float* __restrict__ ga,
                                                 const float* __restrict__ gw,
                                                 const float* __restrict__ gb) {
  __shared__ float scs[FDIM], shs[FDIM];
  int tid = threadIdx.x, w = tid >> 6, l = tid & 63;
  int brow0 = blockIdx.x * 32;
  int lm = l & 15, lk = (l >> 4) * 8;   // lk in {0,8,16,24}
  int ar0 = min(brow0 + lm, NN - 1);
  int ar1 = min(brow0 + 16 + lm, NN - 1);
  size_t abase0 = (size_t)ar0 * 256 + lk;
  size_t abase1 = (size_t)ar1 * 256 + lk;
  const ushort* bp[4];
#pragma unroll
  for (int j = 0; j < 4; j++)
    bp[j] = Bt + (size_t)(w * 64 + j * 16 + lm) * 256 + lk;

  if constexpr (MODE == 1) {
    const float invn = 1.0f / (float)NN;
    float mu = colsum[tid] * invn;
    float ex2 = colsumsq[tid] * invn;
    float a = ga[tid];
    float var = fmaxf(ex2 - (2.f * a - a * a) * mu * mu, 0.f);
    float s = gw[tid] * rsqrtf(var + 1e-5f);
    scs[tid] = s;
    shs[tid] = gb[tid] - s * a * mu;
    __syncthreads();
  }

  floatx4 acc[2][4];
#pragma unroll
  for (int i = 0; i < 2; i++)
#pragma unroll
    for (int j = 0; j < 4; j++) acc[i][j] = floatx4{0.f, 0.f, 0.f, 0.f};

#pragma unroll
  for (int k0 = 0; k0 < 256; k0 += 32) {
    bf16x8 af0, af1;
    if constexpr (MODE == 0) {
      const float* A = (const float*)Ap;
      float4 u0 = *(const float4*)(A + abase0 + k0);
      float4 u1 = *(const float4*)(A + abase0 + k0 + 4);
      float4 v0 = *(const float4*)(A + abase1 + k0);
      float4 v1 = *(const float4*)(A + abase1 + k0 + 4);
      ushort8v a0{f2bf(u0.x), f2bf(u0.y), f2bf(u0.z), f2bf(u0.w),
                  f2bf(u1.x), f2bf(u1.y), f2bf(u1.z), f2bf(u1.w)};
      ushort8v a1{f2bf(v0.x), f2bf(v0.y), f2bf(v0.z), f2bf(v0.w),
                  f2bf(v1.x), f2bf(v1.y), f2bf(v1.z), f2bf(v1.w)};
      af0 = *(bf16x8*)&a0;
      af1 = *(bf16x8*)&a1;
    } else {
      const ushort* A = (const ushort*)Ap;
      ushort8v r0 = *(const ushort8v*)(A + abase0 + k0);
      ushort8v r1 = *(const ushort8v*)(A + abase1 + k0);
      int k = k0 + lk;
      float4 sc0 = *(const float4*)&scs[k];
      float4 sc1 = *(const float4*)&scs[k + 4];
      float4 sh0 = *(const float4*)&shs[k];
      float4 sh1 = *(const float4*)&shs[k + 4];
      ushort8v a0, a1;
#pragma unroll
      for (int j = 0; j < 4; j++) {
        float y0 = fmaf(((const float*)&sc0)[j], bf2f(r0[j]), ((const float*)&sh0)[j]);
        float y1 = fmaf(((const float*)&sc1)[j], bf2f(r0[j + 4]), ((const float*)&sh1)[j]);
        float z0 = fmaf(((const float*)&sc0)[j], bf2f(r1[j]), ((const float*)&sh0)[j]);
        float z1 = fmaf(((const float*)&sc1)[j], bf2f(r1[j + 4]), ((const float*)&sh1)[j]);
        y0 = fmaxf(y0, 0.01f * y0);
        y1 = fmaxf(y1, 0.01f * y1);
        z0 = fmaxf(z0, 0.01f * z0);
        z1 = fmaxf(z1, 0.01f * z1);
        a0[j] = f2bf(y0); a0[j + 4] = f2bf(y1);
        a1[j] = f2bf(z0); a1[j + 4] = f2bf(z1);
      }
      af0 = *(bf16x8*)&a0;
      af1 = *(bf16x8*)&a1;
    }
    bf16x8 bf0 = *(const bf16x8*)(bp[0] + k0);
    bf16x8 bf1 = *(const bf16x8*)(bp[1] + k0);
    bf16x8 bf2 = *(const bf16x8*)(bp[2] + k0);
    bf16x8 bf3 = *(const bf16x8*)(bp[3] + k0);
    acc[0][0] = __builtin_amdgcn_mfma_f32_16x16x32_bf16(af0, bf0, acc[0][0], 0, 0, 0);
    acc[1][0] = __builtin_amdgcn_mfma_f32_16x16x32_bf16(af1, bf0, acc[1][0], 0, 0, 0);
    acc[0][1] = __builtin_amdgcn_mfma_f32_16x16x32_bf16(af0, bf1, acc[0][1], 0, 0, 0);
    acc[1][1] = __builtin_amdgcn_mfma_f32_16x16x32_bf16(af1, bf1, acc[1][1], 0, 0, 0);
    acc[0][2] = __builtin_amdgcn_mfma_f32_16x16x32_bf16(af0, bf2, acc[0][2], 0, 0, 0);
    acc[1][2] = __builtin_amdgcn_mfma_f32_16x16x32_bf16(af1, bf2, acc[1][2], 0, 0, 0);
    acc[0][3] = __builtin_amdgcn_mfma_f32_16x16x32_bf16(af0, bf3, acc[0][3], 0, 0, 0);
    acc[1][3] = __builtin_amdgcn_mfma_f32_16x16x32_bf16(af1, bf3, acc[1][3], 0, 0, 0);
  }

  int quad = l >> 4;
  // ----- C store -----
#pragma unroll
  for (int i = 0; i < 2; i++) {
    int rr0 = brow0 + i * 16 + quad * 4;
#pragma unroll
    for (int j = 0; j < 4; j++) {
      int col = w * 64 + j * 16 + lm;
#pragma unroll
      for (int r = 0; r < 4; r++) {
        int row = rr0 + r;
        if (row < NN) C[(size_t)row * 256 + col] = f2bf(acc[i][j][r]);
      }
    }
  }
  // ----- s/d epilogue: wave w owns head w for rows brow0..brow0+32 -----
  float asv[4], adv[4];
#pragma unroll
  for (int j = 0; j < 4; j++) {
    int col = w * 64 + j * 16 + lm;
    asv[j] = as_[col];
    adv[j] = ad_[col];
  }
#pragma unroll
  for (int i = 0; i < 2; i++) {
#pragma unroll
    for (int r = 0; r < 4; r++) {
      float sp = acc[i][0][r] * asv[0] + acc[i][1][r] * asv[1] +
                 acc[i][2][r] * asv[2] + acc[i][3][r] * asv[3];
      float dp = acc[i][0][r] * adv[0] + acc[i][1][r] * adv[1] +
                 acc[i][2][r] * adv[2] + acc[i][3][r] * adv[3];
      sp += __shfl_xor(sp, 1); dp += __shfl_xor(dp, 1);
      sp += __shfl_xor(sp, 2); dp += __shfl_xor(dp, 2);
      sp += __shfl_xor(sp, 4); dp += __shfl_xor(dp, 4);
      sp += __shfl_xor(sp, 8); dp += __shfl_xor(dp, 8);
      if (lm == 0) {
        int row = brow0 + i * 16 + quad * 4 + r;
        if (row < NN) {
          s_arr[row * HH + w] = sp;
          d_arr[row * HH + w] = dp;
        }
      }
    }
  }
}

// ---------- aggregation: one wave per node; 16-deep gather (R2, proven) ----------
template <bool CONCAT>
__global__ __launch_bounds__(256) void agg_kernel(const ushort* __restrict__ hb,
                                                  const float* __restrict__ s_arr,
                                                  const float* __restrict__ d_arr,
                                                  const int* __restrict__ rowptr,
                                                  const int* __restrict__ csr_src,
                                                  const float* __restrict__ bias,
                                                  void* __restrict__ outp) {
  int w = __builtin_amdgcn_readfirstlane(threadIdx.x >> 6);
  int l = threadIdx.x & 63;
  int head = l >> 4;
  int n = blockIdx.x * 4 + w;
  int beg = rowptr[n], end = rowptr[n + 1];
  float dh = d_arr[n * HH + head];
  float a0 = 0.f, a1 = 0.f, a2 = 0.f, a3 = 0.f, den = 0.f;

  int i = beg;
  // ---- 16-deep main: all loads issued before any consume (max MLP) ----
  for (; i + 16 <= end; i += 16) {
    int ss[16];
#pragma unroll
    for (int t = 0; t < 16; t++) ss[t] = csr_src[i + t];
    float ee[16];
#pragma unroll
    for (int t = 0; t < 16; t++) ee[t] = s_arr[ss[t] * HH + head];
    ushort4s hh[16];
#pragma unroll
    for (int t = 0; t < 16; t++)
      hh[t] = *(const ushort4s*)(hb + (unsigned)(ss[t] * FDIM + l * 4));
#pragma unroll
    for (int t = 0; t < 16; t++) {
      float e = ee[t] + dh;
      e = (e > 0.f) ? e : 0.2f * e;
      float wt = __expf(e);
      den += wt;
      a0 = fmaf(wt, bf2f(hh[t].x), a0);
      a1 = fmaf(wt, bf2f(hh[t].y), a1);
      a2 = fmaf(wt, bf2f(hh[t].z), a2);
      a3 = fmaf(wt, bf2f(hh[t].w), a3);
    }
  }
  // ---- 8-tier ----
  for (; i + 8 <= end; i += 8) {
    int ss[8];
#pragma unroll
    for (int t = 0; t < 8; t++) ss[t] = csr_src[i + t];
    float ee[8];
#pragma unroll
    for (int t = 0; t < 8; t++) ee[t] = s_arr[ss[t] * HH + head];
    ushort4s hh[8];
#pragma unroll
    for (int t = 0; t < 8; t++)
      hh[t] = *(const ushort4s*)(hb + (unsigned)(ss[t] * FDIM + l * 4));
#pragma unroll
    for (int t = 0; t < 8; t++) {
      float e = ee[t] + dh;
      e = (e > 0.f) ? e : 0.2f * e;
      float wt = __expf(e);
      den += wt;
      a0 = fmaf(wt, bf2f(hh[t].x), a0);
      a1 = fmaf(wt, bf2f(hh[t].y), a1);
      a2 = fmaf(wt, bf2f(hh[t].z), a2);
      a3 = fmaf(wt, bf2f(hh[t].w), a3);
    }
  }
  // ---- 4-tier ----
  for (; i + 4 <= end; i += 4) {
    int ss[4];
#pragma unroll
    for (int t = 0; t < 4; t++) ss[t] = csr_src[i + t];
    float ee[4];
#pragma unroll
    for (int t = 0; t < 4; t++) ee[t] = s_arr[ss[t] * HH + head];
    ushort4s hh[4];
#pragma unroll
    for (int t = 0; t < 4; t++)
      hh[t] = *(const ushort4s*)(hb + (unsigned)(ss[t] * FDIM + l * 4));
#pragma unroll
    for (int t = 0; t < 4; t++) {
      float e = ee[t] + dh;
      e = (e > 0.f) ? e : 0.2f * e;
      float wt = __expf(e);
      den += wt;
      a0 = fmaf(wt, bf2f(hh[t].x), a0);
      a1 = fmaf(wt, bf2f(hh[t].y), a1);
      a2 = fmaf(wt, bf2f(hh[t].z), a2);
      a3 = fmaf(wt, bf2f(hh[t].w), a3);
    }
  }
  // ---- scalar tail ----
  for (; i < end; i++) {
    int s0 = csr_src[i];
    float e0 = s_arr[s0 * HH + head] + dh;
    ushort4s h0 = *(const ushort4s*)(hb + (unsigned)(s0 * FDIM + l * 4));
    e0 = (e0 > 0.f) ? e0 : 0.2f * e0;
    float w0 = __expf(e0);
    den += w0;
    a0 = fmaf(w0, bf2f(h0.x), a0); a1 = fmaf(w0, bf2f(h0.y), a1);
    a2 = fmaf(w0, bf2f(h0.z), a2); a3 = fmaf(w0, bf2f(h0.w), a3);
  }
  float inv = 1.0f / den;  // self loop guarantees den > 0
  float r0 = a0 * inv, r1 = a1 * inv, r2 = a2 * inv, r3 = a3 * inv;

  if (CONCAT) {
    float4 bv = ((const float4*)bias)[l];
    ushort4s o;
    o.x = f2bf(r0 + bv.x); o.y = f2bf(r1 + bv.y);
    o.z = f2bf(r2 + bv.z); o.w = f2bf(r3 + bv.w);
    ((ushort4s*)outp)[(unsigned)(n * 64 + l)] = o;
  } else {
    r0 += __shfl_xor(r0, 16); r1 += __shfl_xor(r1, 16);
    r2 += __shfl_xor(r2, 16); r3 += __shfl_xor(r3, 16);
    r0 += __shfl_xor(r0, 32); r1 += __shfl_xor(r1, 32);
    r2 += __shfl_xor(r2, 32); r3 += __shfl_xor(r3, 32);
    if (l < 16) {
      float4 bv = ((const float4*)bias)[l];
      float4 o;
      o.x = 0.25f * r0 + bv.x; o.y = 0.25f * r1 + bv.y;
      o.z = 0.25f * r2 + bv.z; o.w = 0.25f * r3 + bv.w;
      ((float4*)outp)[(unsigned)(n * 16 + l)] = o;
    }
  }
}

// ---------- GraphNorm reduce ----------
__global__ __launch_bounds__(256) void norm_reduce_bf(const ushort* __restrict__ xin,
                                                      float* colsum, float* colsumsq) {
  __shared__ float4 sm1[256], sm2[256];
  int t = threadIdx.x;
  int c4 = (t & 63) * 4;
  int rl = t >> 6;
  int r0 = blockIdx.x * 128;
  int r1 = min(NN, r0 + 128);
  float s0 = 0.f, s1 = 0.f, s2 = 0.f, s3 = 0.f;
  float q0 = 0.f, q1 = 0.f, q2 = 0.f, q3 = 0.f;
  for (int r = r0 + rl; r < r1; r += 4) {
    ushort4s v = *(const ushort4s*)(xin + (size_t)r * FDIM + c4);
    float f0 = bf2f(v.x), f1 = bf2f(v.y), f2 = bf2f(v.z), f3 = bf2f(v.w);
    s0 += f0; q0 += f0 * f0;
    s1 += f1; q1 += f1 * f1;
    s2 += f2; q2 += f2 * f2;
    s3 += f3; q3 += f3 * f3;
  }
  sm1[t] = float4{s0, s1, s2, s3};
  sm2[t] = float4{q0, q1, q2, q3};
  __syncthreads();
  if (t < 64) {
    float4 a = sm1[t], b = sm1[t + 64], c = sm1[t + 128], d = sm1[t + 192];
    atomicAdd(&colsum[c4 + 0], a.x + b.x + c.x + d.x);
    atomicAdd(&colsum[c4 + 1], a.y + b.y + c.y + d.y);
    atomicAdd(&colsum[c4 + 2], a.z + b.z + c.z + d.z);
    atomicAdd(&colsum[c4 + 3], a.w + b.w + c.w + d.w);
    float4 e = sm2[t], f = sm2[t + 64], g = sm2[t + 128], h = sm2[t + 192];
    atomicAdd(&colsumsq[c4 + 0], e.x + f.x + g.x + h.x);
    atomicAdd(&colsumsq[c4 + 1], e.y + f.y + g.y + h.y);
    atomicAdd(&colsumsq[c4 + 2], e.z + f.z + g.z + h.z);
    atomicAdd(&colsumsq[c4 + 3], e.w + f.w + g.w + h.w);
  }
}

__global__ __launch_bounds__(256) void norm_reduce_f32(const float* __restrict__ xin,
                                                       float* colsum, float* colsumsq) {
  int f = threadIdx.x & (CC - 1);
  int rl = threadIdx.x / CC;
  int r0 = blockIdx.x * 128;
  int r1 = min(NN, r0 + 128);
  float s1 = 0.f, s2 = 0.f;
  for (int r = r0 + rl; r < r1; r += 4) {
    float v = xin[(size_t)r * CC + f];
    s1 += v; s2 += v * v;
  }
  atomicAdd(&colsum[f], s1);
  atomicAdd(&colsumsq[f], s2);
}

// ---------- MLP 64->32->16->2 with fused GraphNorm+LeakyReLU on input ----------
__global__ __launch_bounds__(256) void mlp_kernel(const float* __restrict__ xin,
                                                  const float* __restrict__ colsum,
                                                  const float* __restrict__ colsumsq,
                                                  const float* __restrict__ ga,
                                                  const float* __restrict__ gw,
                                                  const float* __restrict__ gb,
                                                  const float* mW0, const float* mb0,
                                                  const float* mW1, const float* mb1,
                                                  const float* mW2, const float* mb2,
                                                  float* __restrict__ out) {
  __shared__ float W0s[64 * 32];
  __shared__ float W1s[32 * 16];
  __shared__ float W2s[16 * 2];
  __shared__ float b0s[32], b1s[16], b2s[2];
  __shared__ float sc[CC], sh[CC];
  int t = threadIdx.x;
  for (int i = t; i < 2048; i += 256) W0s[i] = mW0[i];
  for (int i = t; i < 512; i += 256) W1s[i] = mW1[i];
  if (t < 32) { W2s[t] = mW2[t]; b0s[t] = mb0[t]; }
  if (t < 16) b1s[t] = mb1[t];
  if (t < 2) b2s[t] = mb2[t];
  if (t < CC) {
    const float invn = 1.0f / (float)NN;
    float mu = colsum[t] * invn;
    float ex2 = colsumsq[t] * invn;
    float a = ga[t];
    float var = fmaxf(ex2 - (2.f * a - a * a) * mu * mu, 0.f);
    float s = gw[t] * rsqrtf(var + 1e-5f);
    sc[t] = s; sh[t] = gb[t] - s * a * mu;
  }
  __syncthreads();
  int node = blockIdx.x * 256 + t;
  if (node >= NN) return;
  float in[64];
  const float* xr = xin + (size_t)node * 64;
#pragma unroll
  for (int k = 0; k < 64; k++) {
    float y = sc[k] * xr[k] + sh[k];
    in[k] = (y > 0.f) ? y : 0.01f * y;   // GraphNorm + LeakyReLU(0.01) fused
  }
  float h1[32];
#pragma unroll
  for (int j = 0; j < 32; j++) h1[j] = b0s[j];
#pragma unroll
  for (int k = 0; k < 64; k++) {
    float v = in[k];
#pragma unroll
    for (int j = 0; j < 32; j++) h1[j] += v * W0s[k * 32 + j];
  }
#pragma unroll
  for (int j = 0; j < 32; j++) h1[j] = fmaxf(h1[j], 0.f);
  float h2[16];
#pragma unroll
  for (int j = 0; j < 16; j++) h2[j] = b1s[j];
#pragma unroll
  for (int k = 0; k < 32; k++) {
    float v = h1[k];
#pragma unroll
    for (int j = 0; j < 16; j++) h2[j] += v * W1s[k * 16 + j];
  }
#pragma unroll
  for (int j = 0; j < 16; j++) h2[j] = fmaxf(h2[j], 0.f);
  float o0 = b2s[0], o1 = b2s[1];
#pragma unroll
  for (int k = 0; k < 16; k++) {
    o0 += h2[k] * W2s[k * 2 + 0];
    o1 += h2[k] * W2s[k * 2 + 1];
  }
  out[(size_t)node * 2 + 0] = o0;
  out[(size_t)node * 2 + 1] = o1;
}

extern "C" void kernel_launch(void* const* d_in, const int* in_sizes, int n_in,
                              void* d_out, int out_size, void* d_ws, size_t ws_size,
                              hipStream_t stream) {
  const float* x = (const float*)d_in[0];
  const void* ei = d_in[1];
  const float* W[3]   = {(const float*)d_in[2],  (const float*)d_in[9],  (const float*)d_in[16]};
  const float* as_[3] = {(const float*)d_in[3],  (const float*)d_in[10], (const float*)d_in[17]};
  const float* ad_[3] = {(const float*)d_in[4],  (const float*)d_in[11], (const float*)d_in[18]};
  const float* b_[3]  = {(const float*)d_in[5],  (const float*)d_in[12], (const float*)d_in[19]};
  const float* gw[3]  = {(const float*)d_in[6],  (const float*)d_in[13], (const float*)d_in[20]};
  const float* gb[3]  = {(const float*)d_in[7],  (const float*)d_in[14], (const float*)d_in[21]};
  const float* ga[3]  = {(const float*)d_in[8],  (const float*)d_in[15], (const float*)d_in[22]};
  const float* mW0 = (const float*)d_in[23];
  const float* mb0 = (const float*)d_in[24];
  const float* mW1 = (const float*)d_in[25];
  const float* mb1 = (const float*)d_in[26];
  const float* mW2 = (const float*)d_in[27];
  const float* mb2 = (const float*)d_in[28];
  float* out = (float*)d_out;

  // edge-index dtype from byte size: int64 => 2*EE*8 bytes
  int is64 = (in_sizes[1] == (int)(2u * EE * 8u)) ? 1 : 0;

  char* ws = (char*)d_ws;
  size_t off = 0;
  auto take = [&](size_t bytes) -> char* {
    char* p = ws + off;
    off = (off + bytes + 255) & ~(size_t)255;
    return p;
  };
  ushort* hb    = (ushort*)take((size_t)NN * FDIM * 2);
  ushort* aggb  = (ushort*)take((size_t)NN * FDIM * 2);
  float* bufD   = (float*)take((size_t)NN * CC * 4);
  ushort* Wt[3];
  for (int i = 0; i < 3; i++) Wt[i] = (ushort*)take((size_t)256 * 256 * 2);
  float* s_arr  = (float*)take((size_t)NN * HH * 4);
  float* d_arr  = (float*)take((size_t)NN * HH * 4);
  // zero-region: deg + 3 per-layer stat buffers (colsum|colsumsq each) -> ONE memset
  char* zbase   = (char*)take(0);
  int* deg      = (int*)take((size_t)NN * 4);
  float* cs[3];
  for (int i = 0; i < 3; i++) cs[i] = (float*)take(2048);   // [0:256)=colsum, [256:512)=colsumsq
  size_t zlen   = (size_t)(((char*)cs[2] + 2048) - zbase);
  int* cursor   = (int*)take((size_t)NN * 4);
  int* rowptr   = (int*)take((size_t)(NN + 1) * 4);
  int* csr_src  = (int*)take((size_t)ET * 4);
  int* bsum     = (int*)take(512);
  int* boff     = (int*)take(512);

  hipMemsetAsync(zbase, 0, zlen, stream);   // deg + all 3 layers' norm stats

  // CSR build (reused by all 3 layers)
  degree_kernel<<<(ET + 255) / 256, 256, 0, stream>>>(ei, is64, deg);
  scan1_kernel<<<SCAN_NB, SCAN_BLK, 0, stream>>>(deg, rowptr, bsum);
  scan2_kernel<<<1, 128, 0, stream>>>(bsum, boff, rowptr);
  scan3_kernel<<<SCAN_NB, SCAN_BLK, 0, stream>>>(rowptr, cursor, boff);
  fill_kernel<<<(ET + 255) / 256, 256, 0, stream>>>(ei, is64, cursor, csr_src);

  // weight prep (x is consumed in f32 directly by layer-0 gemm)
  conv_w_kernel<<<dim3(256, 3), 256, 0, stream>>>(W[0], W[1], W[2], Wt[0], Wt[1], Wt[2]);

  int ggrid = (NN + 31) / 32;   // 1563
  for (int L = 0; L < 3; L++) {
    if (L == 0)
      gemm_bf16<0><<<ggrid, 256, 0, stream>>>((const void*)x, Wt[0], hb,
                                              as_[0], ad_[0], s_arr, d_arr,
                                              nullptr, nullptr, nullptr, nullptr, nullptr);
    else
      gemm_bf16<1><<<ggrid, 256, 0, stream>>>((const void*)aggb, Wt[L], hb,
                                              as_[L], ad_[L], s_arr, d_arr,
                                              cs[L - 1], cs[L - 1] + 256,
                                              ga[L - 1], gw[L - 1], gb[L - 1]);
    if (L < 2) {
      agg_kernel<true><<<NN / 4, 256, 0, stream>>>(hb, s_arr, d_arr, rowptr, csr_src, b_[L], aggb);
      norm_reduce_bf<<<(NN + 127) / 128, 256, 0, stream>>>(aggb, cs[L], cs[L] + 256);
    } else {
      agg_kernel<false><<<NN / 4, 256, 0, stream>>>(hb, s_arr, d_arr, rowptr, csr_src, b_[L], bufD);
      norm_reduce_f32<<<(NN + 127) / 128, 256, 0, stream>>>(bufD, cs[2], cs[2] + 256);
    }
  }
  mlp_kernel<<<(NN + 255) / 256, 256, 0, stream>>>(bufD, cs[2], cs[2] + 256,
                                                   ga[2], gw[2], gb[2],
                                                   mW0, mb0, mW1, mb1, mW2, mb2, out);
}

// Round 6
// 730.847 us; speedup vs baseline: 1.0018x; 1.0018x over previous
//
#include <hip/hip_runtime.h>

#define NN 50000
#define EE 800000
#define ET 850000   // EE + NN self loops
#define HH 4
#define CC 64
#define FDIM 256    // HH*CC

#define SCAN_BLK 512
#define SCAN_NB ((NN + SCAN_BLK - 1) / SCAN_BLK)   // 98

typedef unsigned short ushort;
typedef __bf16 bf16x8 __attribute__((ext_vector_type(8)));
typedef float floatx4 __attribute__((ext_vector_type(4)));
typedef ushort ushort8v __attribute__((ext_vector_type(8)));
struct ushort4s { ushort x, y, z, w; };

__device__ __forceinline__ ushort f2bf(float f) {
  union { float f; unsigned u; } v; v.f = f;
  unsigned r = v.u + 0x7fffu + ((v.u >> 16) & 1u);  // RNE
  return (ushort)(r >> 16);
}
__device__ __forceinline__ float bf2f(ushort u) {
  return __uint_as_float(((unsigned)u) << 16);
}

// ---------- edge-index dtype handling (is64 decided HOST-side from in_sizes) ----------
__device__ __forceinline__ int get_edge(const void* p, int is64, long long idx) {
  if (is64) return (int)((const long long*)p)[idx];
  return ((const int*)p)[idx];
}

// ---------- CSR build over dst ----------
__global__ void degree_kernel(const void* eidx, int is64, int* deg) {
  int k = blockIdx.x * blockDim.x + threadIdx.x;
  if (k >= ET) return;
  int dst = (k < EE) ? get_edge(eidx, is64, (long long)EE + k) : (k - EE);
  atomicAdd(&deg[dst], 1);
}

__global__ __launch_bounds__(SCAN_BLK) void scan1_kernel(const int* __restrict__ deg,
                                                         int* __restrict__ rowptr,
                                                         int* __restrict__ bsum) {
  __shared__ int sm[SCAN_BLK];
  int t = threadIdx.x;
  int i = blockIdx.x * SCAN_BLK + t;
  int v = (i < NN) ? deg[i] : 0;
  sm[t] = v;
  __syncthreads();
#pragma unroll
  for (int o = 1; o < SCAN_BLK; o <<= 1) {
    int u = (t >= o) ? sm[t - o] : 0;
    __syncthreads();
    sm[t] += u;
    __syncthreads();
  }
  if (i < NN) rowptr[i] = sm[t] - v;                 // local exclusive
  if (t == SCAN_BLK - 1) bsum[blockIdx.x] = sm[t];   // block total
}

__global__ __launch_bounds__(128) void scan2_kernel(const int* __restrict__ bsum,
                                                    int* __restrict__ boff,
                                                    int* __restrict__ rowptr) {
  __shared__ int sm[128];
  int t = threadIdx.x;
  int v = (t < SCAN_NB) ? bsum[t] : 0;
  sm[t] = v;
  __syncthreads();
#pragma unroll
  for (int o = 1; o < 128; o <<= 1) {
    int u = (t >= o) ? sm[t - o] : 0;
    __syncthreads();
    sm[t] += u;
    __syncthreads();
  }
  if (t < SCAN_NB) boff[t] = sm[t] - v;  // exclusive block offset
  if (t == 0) rowptr[NN] = ET;
}

__global__ __launch_bounds__(SCAN_BLK) void scan3_kernel(int* __restrict__ rowptr,
                                                         int* __restrict__ cursor,
                                                         const int* __restrict__ boff) {
  int i = blockIdx.x * SCAN_BLK + threadIdx.x;
  if (i >= NN) return;
  int v = rowptr[i] + boff[blockIdx.x];
  rowptr[i] = v;
  cursor[i] = v;
}

__global__ void fill_kernel(const void* eidx, int is64, int* cursor, int* csr_src) {
  int k = blockIdx.x * blockDim.x + threadIdx.x;
  if (k >= ET) return;
  int src, dst;
  if (k < EE) {
    src = get_edge(eidx, is64, k);
    dst = get_edge(eidx, is64, (long long)EE + k);
  } else {
    src = dst = k - EE;
  }
  int pos = atomicAdd(&cursor[dst], 1);
  csr_src[pos] = src;
}

// all three weight transposes in one dispatch (grid.y selects the matrix)
__global__ void conv_w_kernel(const float* __restrict__ W0, const float* __restrict__ W1,
                              const float* __restrict__ W2,
                              ushort* __restrict__ T0, ushort* __restrict__ T1,
                              ushort* __restrict__ T2) {
  const float* W = (blockIdx.y == 0) ? W0 : (blockIdx.y == 1) ? W1 : W2;
  ushort* Wt = (blockIdx.y == 0) ? T0 : (blockIdx.y == 1) ? T1 : T2;
  int idx = blockIdx.x * 256 + threadIdx.x;  // 65536
  int k = idx >> 8, n = idx & 255;
  Wt[n * 256 + k] = f2bf(W[idx]);  // transpose: Wt[n][k]
}

// ---------- bf16 MFMA GEMM: LDS-free, register-PIPELINED K-loop (R6) ----------
// R5 counters: MfmaUtil 3.6%, VALU 11%, HBM 10%, VGPR 52 -> compiler allocated
// ONE k-step of load regs => serial {issue 6 loads -> vmcnt(0) -> 8 MFMA}.
// Little's law: need ~5KB/CU in flight; serial sustains <1KB -> 4-5x slow.
// R6: explicit prefetch pipeline (depth 2 for MODE 0's fat f32 A stages,
// depth 3 for MODE 1), fully unrolled so slot indices are compile-time
// (rule #20). VGPR ~116-124: stays at 4 waves/SIMD (128-VGPR step).
// Sustained in-flight: 192-288B/wave x 16 waves/CU ~ 3-4.6KB/CU.
template <int MODE>
__global__ __launch_bounds__(256) void gemm_bf16(const void* __restrict__ Ap,
                                                 const ushort* __restrict__ Bt,
                                                 ushort* __restrict__ C,
                                                 const float* __restrict__ as_,
                                                 const float* __restrict__ ad_,
                                                 float* __restrict__ s_arr,
                                                 float* __restrict__ d_arr,
                                                 const float* __restrict__ colsum,
                                                 const float* __restrict__ colsumsq,
                                                 const float* __restrict__ ga,
                                                 const float* __restrict__ gw,
                                                 const float* __restrict__ gb) {
  __shared__ float scs[FDIM], shs[FDIM];
  int tid = threadIdx.x, w = tid >> 6, l = tid & 63;
  int brow0 = blockIdx.x * 32;
  int lm = l & 15, lk = (l >> 4) * 8;   // lk in {0,8,16,24}
  int ar0 = min(brow0 + lm, NN - 1);
  int ar1 = min(brow0 + 16 + lm, NN - 1);
  size_t abase0 = (size_t)ar0 * 256 + lk;
  size_t abase1 = (size_t)ar1 * 256 + lk;
  const ushort* bp[4];
#pragma unroll
  for (int j = 0; j < 4; j++)
    bp[j] = Bt + (size_t)(w * 64 + j * 16 + lm) * 256 + lk;

  if constexpr (MODE == 1) {
    const float invn = 1.0f / (float)NN;
    float mu = colsum[tid] * invn;
    float ex2 = colsumsq[tid] * invn;
    float a = ga[tid];
    float var = fmaxf(ex2 - (2.f * a - a * a) * mu * mu, 0.f);
    float s = gw[tid] * rsqrtf(var + 1e-5f);
    scs[tid] = s;
    shs[tid] = gb[tid] - s * a * mu;
    __syncthreads();
  }

  floatx4 acc[2][4];
#pragma unroll
  for (int i = 0; i < 2; i++)
#pragma unroll
    for (int j = 0; j < 4; j++) acc[i][j] = floatx4{0.f, 0.f, 0.f, 0.f};

  if constexpr (MODE == 0) {
    const float* A = (const float*)Ap;
    // depth-2 pipeline: stage = {4x float4 A raw, 4x bf16x8 B} = 32 VGPR
    float4 u0[2], u1[2], v0[2], v1[2];
    bf16x8 sb0[2], sb1[2], sb2[2], sb3[2];
    auto LD = [&](int k0, int s) {
      u0[s] = *(const float4*)(A + abase0 + k0);
      u1[s] = *(const float4*)(A + abase0 + k0 + 4);
      v0[s] = *(const float4*)(A + abase1 + k0);
      v1[s] = *(const float4*)(A + abase1 + k0 + 4);
      sb0[s] = *(const bf16x8*)(bp[0] + k0);
      sb1[s] = *(const bf16x8*)(bp[1] + k0);
      sb2[s] = *(const bf16x8*)(bp[2] + k0);
      sb3[s] = *(const bf16x8*)(bp[3] + k0);
    };
    LD(0, 0);
#pragma unroll
    for (int s = 0; s < 8; s++) {
      if (s < 7) LD((s + 1) * 32, (s + 1) & 1);
      int c = s & 1;
      ushort8v a0{f2bf(u0[c].x), f2bf(u0[c].y), f2bf(u0[c].z), f2bf(u0[c].w),
                  f2bf(u1[c].x), f2bf(u1[c].y), f2bf(u1[c].z), f2bf(u1[c].w)};
      ushort8v a1{f2bf(v0[c].x), f2bf(v0[c].y), f2bf(v0[c].z), f2bf(v0[c].w),
                  f2bf(v1[c].x), f2bf(v1[c].y), f2bf(v1[c].z), f2bf(v1[c].w)};
      bf16x8 af0 = *(bf16x8*)&a0;
      bf16x8 af1 = *(bf16x8*)&a1;
      acc[0][0] = __builtin_amdgcn_mfma_f32_16x16x32_bf16(af0, sb0[c], acc[0][0], 0, 0, 0);
      acc[1][0] = __builtin_amdgcn_mfma_f32_16x16x32_bf16(af1, sb0[c], acc[1][0], 0, 0, 0);
      acc[0][1] = __builtin_amdgcn_mfma_f32_16x16x32_bf16(af0, sb1[c], acc[0][1], 0, 0, 0);
      acc[1][1] = __builtin_amdgcn_mfma_f32_16x16x32_bf16(af1, sb1[c], acc[1][1], 0, 0, 0);
      acc[0][2] = __builtin_amdgcn_mfma_f32_16x16x32_bf16(af0, sb2[c], acc[0][2], 0, 0, 0);
      acc[1][2] = __builtin_amdgcn_mfma_f32_16x16x32_bf16(af1, sb2[c], acc[1][2], 0, 0, 0);
      acc[0][3] = __builtin_amdgcn_mfma_f32_16x16x32_bf16(af0, sb3[c], acc[0][3], 0, 0, 0);
      acc[1][3] = __builtin_amdgcn_mfma_f32_16x16x32_bf16(af1, sb3[c], acc[1][3], 0, 0, 0);
    }
  } else {
    const ushort* A = (const ushort*)Ap;
    // depth-3 pipeline: stage = {2x ushort8v A raw, 4x bf16x8 B} = 24 VGPR
    ushort8v r0[3], r1[3];
    bf16x8 sb0[3], sb1[3], sb2[3], sb3[3];
    auto LD = [&](int k0, int s) {
      r0[s] = *(const ushort8v*)(A + abase0 + k0);
      r1[s] = *(const ushort8v*)(A + abase1 + k0);
      sb0[s] = *(const bf16x8*)(bp[0] + k0);
      sb1[s] = *(const bf16x8*)(bp[1] + k0);
      sb2[s] = *(const bf16x8*)(bp[2] + k0);
      sb3[s] = *(const bf16x8*)(bp[3] + k0);
    };
    LD(0, 0);
    LD(32, 1);
#pragma unroll
    for (int s = 0; s < 8; s++) {
      if (s < 6) LD((s + 2) * 32, (s + 2) % 3);
      int c = s % 3;
      int k = s * 32 + lk;
      float4 sc0 = *(const float4*)&scs[k];
      float4 sc1 = *(const float4*)&scs[k + 4];
      float4 sh0 = *(const float4*)&shs[k];
      float4 sh1 = *(const float4*)&shs[k + 4];
      ushort8v a0, a1;
#pragma unroll
      for (int j = 0; j < 4; j++) {
        float y0 = fmaf(((const float*)&sc0)[j], bf2f(r0[c][j]), ((const float*)&sh0)[j]);
        float y1 = fmaf(((const float*)&sc1)[j], bf2f(r0[c][j + 4]), ((const float*)&sh1)[j]);
        float z0 = fmaf(((const float*)&sc0)[j], bf2f(r1[c][j]), ((const float*)&sh0)[j]);
        float z1 = fmaf(((const float*)&sc1)[j], bf2f(r1[c][j + 4]), ((const float*)&sh1)[j]);
        y0 = fmaxf(y0, 0.01f * y0);
        y1 = fmaxf(y1, 0.01f * y1);
        z0 = fmaxf(z0, 0.01f * z0);
        z1 = fmaxf(z1, 0.01f * z1);
        a0[j] = f2bf(y0); a0[j + 4] = f2bf(y1);
        a1[j] = f2bf(z0); a1[j + 4] = f2bf(z1);
      }
      bf16x8 af0 = *(bf16x8*)&a0;
      bf16x8 af1 = *(bf16x8*)&a1;
      acc[0][0] = __builtin_amdgcn_mfma_f32_16x16x32_bf16(af0, sb0[c], acc[0][0], 0, 0, 0);
      acc[1][0] = __builtin_amdgcn_mfma_f32_16x16x32_bf16(af1, sb0[c], acc[1][0], 0, 0, 0);
      acc[0][1] = __builtin_amdgcn_mfma_f32_16x16x32_bf16(af0, sb1[c], acc[0][1], 0, 0, 0);
      acc[1][1] = __builtin_amdgcn_mfma_f32_16x16x32_bf16(af1, sb1[c], acc[1][1], 0, 0, 0);
      acc[0][2] = __builtin_amdgcn_mfma_f32_16x16x32_bf16(af0, sb2[c], acc[0][2], 0, 0, 0);
      acc[1][2] = __builtin_amdgcn_mfma_f32_16x16x32_bf16(af1, sb2[c], acc[1][2], 0, 0, 0);
      acc[0][3] = __builtin_amdgcn_mfma_f32_16x16x32_bf16(af0, sb3[c], acc[0][3], 0, 0, 0);
      acc[1][3] = __builtin_amdgcn_mfma_f32_16x16x32_bf16(af1, sb3[c], acc[1][3], 0, 0, 0);
    }
  }

  int quad = l >> 4;
  // ----- C store -----
#pragma unroll
  for (int i = 0; i < 2; i++) {
    int rr0 = brow0 + i * 16 + quad * 4;
#pragma unroll
    for (int j = 0; j < 4; j++) {
      int col = w * 64 + j * 16 + lm;
#pragma unroll
      for (int r = 0; r < 4; r++) {
        int row = rr0 + r;
        if (row < NN) C[(size_t)row * 256 + col] = f2bf(acc[i][j][r]);
      }
    }
  }
  // ----- s/d epilogue: wave w owns head w for rows brow0..brow0+32 -----
  float asv[4], adv[4];
#pragma unroll
  for (int j = 0; j < 4; j++) {
    int col = w * 64 + j * 16 + lm;
    asv[j] = as_[col];
    adv[j] = ad_[col];
  }
#pragma unroll
  for (int i = 0; i < 2; i++) {
#pragma unroll
    for (int r = 0; r < 4; r++) {
      float sp = acc[i][0][r] * asv[0] + acc[i][1][r] * asv[1] +
                 acc[i][2][r] * asv[2] + acc[i][3][r] * asv[3];
      float dp = acc[i][0][r] * adv[0] + acc[i][1][r] * adv[1] +
                 acc[i][2][r] * adv[2] + acc[i][3][r] * adv[3];
      sp += __shfl_xor(sp, 1); dp += __shfl_xor(dp, 1);
      sp += __shfl_xor(sp, 2); dp += __shfl_xor(dp, 2);
      sp += __shfl_xor(sp, 4); dp += __shfl_xor(dp, 4);
      sp += __shfl_xor(sp, 8); dp += __shfl_xor(dp, 8);
      if (lm == 0) {
        int row = brow0 + i * 16 + quad * 4 + r;
        if (row < NN) {
          s_arr[row * HH + w] = sp;
          d_arr[row * HH + w] = dp;
        }
      }
    }
  }
}

// ---------- aggregation: one wave per node; 16-deep gather (R2, proven) ----------
template <bool CONCAT>
__global__ __launch_bounds__(256) void agg_kernel(const ushort* __restrict__ hb,
                                                  const float* __restrict__ s_arr,
                                                  const float* __restrict__ d_arr,
                                                  const int* __restrict__ rowptr,
                                                  const int* __restrict__ csr_src,
                                                  const float* __restrict__ bias,
                                                  void* __restrict__ outp) {
  int w = __builtin_amdgcn_readfirstlane(threadIdx.x >> 6);
  int l = threadIdx.x & 63;
  int head = l >> 4;
  int n = blockIdx.x * 4 + w;
  int beg = rowptr[n], end = rowptr[n + 1];
  float dh = d_arr[n * HH + head];
  float a0 = 0.f, a1 = 0.f, a2 = 0.f, a3 = 0.f, den = 0.f;

  int i = beg;
  // ---- 16-deep main: all loads issued before any consume (max MLP) ----
  for (; i + 16 <= end; i += 16) {
    int ss[16];
#pragma unroll
    for (int t = 0; t < 16; t++) ss[t] = csr_src[i + t];
    float ee[16];
#pragma unroll
    for (int t = 0; t < 16; t++) ee[t] = s_arr[ss[t] * HH + head];
    ushort4s hh[16];
#pragma unroll
    for (int t = 0; t < 16; t++)
      hh[t] = *(const ushort4s*)(hb + (unsigned)(ss[t] * FDIM + l * 4));
#pragma unroll
    for (int t = 0; t < 16; t++) {
      float e = ee[t] + dh;
      e = (e > 0.f) ? e : 0.2f * e;
      float wt = __expf(e);
      den += wt;
      a0 = fmaf(wt, bf2f(hh[t].x), a0);
      a1 = fmaf(wt, bf2f(hh[t].y), a1);
      a2 = fmaf(wt, bf2f(hh[t].z), a2);
      a3 = fmaf(wt, bf2f(hh[t].w), a3);
    }
  }
  // ---- 8-tier ----
  for (; i + 8 <= end; i += 8) {
    int ss[8];
#pragma unroll
    for (int t = 0; t < 8; t++) ss[t] = csr_src[i + t];
    float ee[8];
#pragma unroll
    for (int t = 0; t < 8; t++) ee[t] = s_arr[ss[t] * HH + head];
    ushort4s hh[8];
#pragma unroll
    for (int t = 0; t < 8; t++)
      hh[t] = *(const ushort4s*)(hb + (unsigned)(ss[t] * FDIM + l * 4));
#pragma unroll
    for (int t = 0; t < 8; t++) {
      float e = ee[t] + dh;
      e = (e > 0.f) ? e : 0.2f * e;
      float wt = __expf(e);
      den += wt;
      a0 = fmaf(wt, bf2f(hh[t].x), a0);
      a1 = fmaf(wt, bf2f(hh[t].y), a1);
      a2 = fmaf(wt, bf2f(hh[t].z), a2);
      a3 = fmaf(wt, bf2f(hh[t].w), a3);
    }
  }
  // ---- 4-tier ----
  for (; i + 4 <= end; i += 4) {
    int ss[4];
#pragma unroll
    for (int t = 0; t < 4; t++) ss[t] = csr_src[i + t];
    float ee[4];
#pragma unroll
    for (int t = 0; t < 4; t++) ee[t] = s_arr[ss[t] * HH + head];
    ushort4s hh[4];
#pragma unroll
    for (int t = 0; t < 4; t++)
      hh[t] = *(const ushort4s*)(hb + (unsigned)(ss[t] * FDIM + l * 4));
#pragma unroll
    for (int t = 0; t < 4; t++) {
      float e = ee[t] + dh;
      e = (e > 0.f) ? e : 0.2f * e;
      float wt = __expf(e);
      den += wt;
      a0 = fmaf(wt, bf2f(hh[t].x), a0);
      a1 = fmaf(wt, bf2f(hh[t].y), a1);
      a2 = fmaf(wt, bf2f(hh[t].z), a2);
      a3 = fmaf(wt, bf2f(hh[t].w), a3);
    }
  }
  // ---- scalar tail ----
  for (; i < end; i++) {
    int s0 = csr_src[i];
    float e0 = s_arr[s0 * HH + head] + dh;
    ushort4s h0 = *(const ushort4s*)(hb + (unsigned)(s0 * FDIM + l * 4));
    e0 = (e0 > 0.f) ? e0 : 0.2f * e0;
    float w0 = __expf(e0);
    den += w0;
    a0 = fmaf(w0, bf2f(h0.x), a0); a1 = fmaf(w0, bf2f(h0.y), a1);
    a2 = fmaf(w0, bf2f(h0.z), a2); a3 = fmaf(w0, bf2f(h0.w), a3);
  }
  float inv = 1.0f / den;  // self loop guarantees den > 0
  float r0 = a0 * inv, r1 = a1 * inv, r2 = a2 * inv, r3 = a3 * inv;

  if (CONCAT) {
    float4 bv = ((const float4*)bias)[l];
    ushort4s o;
    o.x = f2bf(r0 + bv.x); o.y = f2bf(r1 + bv.y);
    o.z = f2bf(r2 + bv.z); o.w = f2bf(r3 + bv.w);
    ((ushort4s*)outp)[(unsigned)(n * 64 + l)] = o;
  } else {
    r0 += __shfl_xor(r0, 16); r1 += __shfl_xor(r1, 16);
    r2 += __shfl_xor(r2, 16); r3 += __shfl_xor(r3, 16);
    r0 += __shfl_xor(r0, 32); r1 += __shfl_xor(r1, 32);
    r2 += __shfl_xor(r2, 32); r3 += __shfl_xor(r3, 32);
    if (l < 16) {
      float4 bv = ((const float4*)bias)[l];
      float4 o;
      o.x = 0.25f * r0 + bv.x; o.y = 0.25f * r1 + bv.y;
      o.z = 0.25f * r2 + bv.z; o.w = 0.25f * r3 + bv.w;
      ((float4*)outp)[(unsigned)(n * 16 + l)] = o;
    }
  }
}

// ---------- GraphNorm reduce ----------
__global__ __launch_bounds__(256) void norm_reduce_bf(const ushort* __restrict__ xin,
                                                      float* colsum, float* colsumsq) {
  __shared__ float4 sm1[256], sm2[256];
  int t = threadIdx.x;
  int c4 = (t & 63) * 4;
  int rl = t >> 6;
  int r0 = blockIdx.x * 128;
  int r1 = min(NN, r0 + 128);
  float s0 = 0.f, s1 = 0.f, s2 = 0.f, s3 = 0.f;
  float q0 = 0.f, q1 = 0.f, q2 = 0.f, q3 = 0.f;
  for (int r = r0 + rl; r < r1; r += 4) {
    ushort4s v = *(const ushort4s*)(xin + (size_t)r * FDIM + c4);
    float f0 = bf2f(v.x), f1 = bf2f(v.y), f2 = bf2f(v.z), f3 = bf2f(v.w);
    s0 += f0; q0 += f0 * f0;
    s1 += f1; q1 += f1 * f1;
    s2 += f2; q2 += f2 * f2;
    s3 += f3; q3 += f3 * f3;
  }
  sm1[t] = float4{s0, s1, s2, s3};
  sm2[t] = float4{q0, q1, q2, q3};
  __syncthreads();
  if (t < 64) {
    float4 a = sm1[t], b = sm1[t + 64], c = sm1[t + 128], d = sm1[t + 192];
    atomicAdd(&colsum[c4 + 0], a.x + b.x + c.x + d.x);
    atomicAdd(&colsum[c4 + 1], a.y + b.y + c.y + d.y);
    atomicAdd(&colsum[c4 + 2], a.z + b.z + c.z + d.z);
    atomicAdd(&colsum[c4 + 3], a.w + b.w + c.w + d.w);
    float4 e = sm2[t], f = sm2[t + 64], g = sm2[t + 128], h = sm2[t + 192];
    atomicAdd(&colsumsq[c4 + 0], e.x + f.x + g.x + h.x);
    atomicAdd(&colsumsq[c4 + 1], e.y + f.y + g.y + h.y);
    atomicAdd(&colsumsq[c4 + 2], e.z + f.z + g.z + h.z);
    atomicAdd(&colsumsq[c4 + 3], e.w + f.w + g.w + h.w);
  }
}

__global__ __launch_bounds__(256) void norm_reduce_f32(const float* __restrict__ xin,
                                                       float* colsum, float* colsumsq) {
  int f = threadIdx.x & (CC - 1);
  int rl = threadIdx.x / CC;
  int r0 = blockIdx.x * 128;
  int r1 = min(NN, r0 + 128);
  float s1 = 0.f, s2 = 0.f;
  for (int r = r0 + rl; r < r1; r += 4) {
    float v = xin[(size_t)r * CC + f];
    s1 += v; s2 += v * v;
  }
  atomicAdd(&colsum[f], s1);
  atomicAdd(&colsumsq[f], s2);
}

// ---------- MLP 64->32->16->2 with fused GraphNorm+LeakyReLU on input ----------
__global__ __launch_bounds__(256) void mlp_kernel(const float* __restrict__ xin,
                                                  const float* __restrict__ colsum,
                                                  const float* __restrict__ colsumsq,
                                                  const float* __restrict__ ga,
                                                  const float* __restrict__ gw,
                                                  const float* __restrict__ gb,
                                                  const float* mW0, const float* mb0,
                                                  const float* mW1, const float* mb1,
                                                  const float* mW2, const float* mb2,
                                                  float* __restrict__ out) {
  __shared__ float W0s[64 * 32];
  __shared__ float W1s[32 * 16];
  __shared__ float W2s[16 * 2];
  __shared__ float b0s[32], b1s[16], b2s[2];
  __shared__ float sc[CC], sh[CC];
  int t = threadIdx.x;
  for (int i = t; i < 2048; i += 256) W0s[i] = mW0[i];
  for (int i = t; i < 512; i += 256) W1s[i] = mW1[i];
  if (t < 32) { W2s[t] = mW2[t]; b0s[t] = mb0[t]; }
  if (t < 16) b1s[t] = mb1[t];
  if (t < 2) b2s[t] = mb2[t];
  if (t < CC) {
    const float invn = 1.0f / (float)NN;
    float mu = colsum[t] * invn;
    float ex2 = colsumsq[t] * invn;
    float a = ga[t];
    float var = fmaxf(ex2 - (2.f * a - a * a) * mu * mu, 0.f);
    float s = gw[t] * rsqrtf(var + 1e-5f);
    sc[t] = s; sh[t] = gb[t] - s * a * mu;
  }
  __syncthreads();
  int node = blockIdx.x * 256 + t;
  if (node >= NN) return;
  float in[64];
  const float* xr = xin + (size_t)node * 64;
#pragma unroll
  for (int k = 0; k < 64; k++) {
    float y = sc[k] * xr[k] + sh[k];
    in[k] = (y > 0.f) ? y : 0.01f * y;   // GraphNorm + LeakyReLU(0.01) fused
  }
  float h1[32];
#pragma unroll
  for (int j = 0; j < 32; j++) h1[j] = b0s[j];
#pragma unroll
  for (int k = 0; k < 64; k++) {
    float v = in[k];
#pragma unroll
    for (int j = 0; j < 32; j++) h1[j] += v * W0s[k * 32 + j];
  }
#pragma unroll
  for (int j = 0; j < 32; j++) h1[j] = fmaxf(h1[j], 0.f);
  float h2[16];
#pragma unroll
  for (int j = 0; j < 16; j++) h2[j] = b1s[j];
#pragma unroll
  for (int k = 0; k < 32; k++) {
    float v = h1[k];
#pragma unroll
    for (int j = 0; j < 16; j++) h2[j] += v * W1s[k * 16 + j];
  }
#pragma unroll
  for (int j = 0; j < 16; j++) h2[j] = fmaxf(h2[j], 0.f);
  float o0 = b2s[0], o1 = b2s[1];
#pragma unroll
  for (int k = 0; k < 16; k++) {
    o0 += h2[k] * W2s[k * 2 + 0];
    o1 += h2[k] * W2s[k * 2 + 1];
  }
  out[(size_t)node * 2 + 0] = o0;
  out[(size_t)node * 2 + 1] = o1;
}

extern "C" void kernel_launch(void* const* d_in, const int* in_sizes, int n_in,
                              void* d_out, int out_size, void* d_ws, size_t ws_size,
                              hipStream_t stream) {
  const float* x = (const float*)d_in[0];
  const void* ei = d_in[1];
  const float* W[3]   = {(const float*)d_in[2],  (const float*)d_in[9],  (const float*)d_in[16]};
  const float* as_[3] = {(const float*)d_in[3],  (const float*)d_in[10], (const float*)d_in[17]};
  const float* ad_[3] = {(const float*)d_in[4],  (const float*)d_in[11], (const float*)d_in[18]};
  const float* b_[3]  = {(const float*)d_in[5],  (const float*)d_in[12], (const float*)d_in[19]};
  const float* gw[3]  = {(const float*)d_in[6],  (const float*)d_in[13], (const float*)d_in[20]};
  const float* gb[3]  = {(const float*)d_in[7],  (const float*)d_in[14], (const float*)d_in[21]};
  const float* ga[3]  = {(const float*)d_in[8],  (const float*)d_in[15], (const float*)d_in[22]};
  const float* mW0 = (const float*)d_in[23];
  const float* mb0 = (const float*)d_in[24];
  const float* mW1 = (const float*)d_in[25];
  const float* mb1 = (const float*)d_in[26];
  const float* mW2 = (const float*)d_in[27];
  const float* mb2 = (const float*)d_in[28];
  float* out = (float*)d_out;

  // edge-index dtype from byte size: int64 => 2*EE*8 bytes
  int is64 = (in_sizes[1] == (int)(2u * EE * 8u)) ? 1 : 0;

  char* ws = (char*)d_ws;
  size_t off = 0;
  auto take = [&](size_t bytes) -> char* {
    char* p = ws + off;
    off = (off + bytes + 255) & ~(size_t)255;
    return p;
  };
  ushort* hb    = (ushort*)take((size_t)NN * FDIM * 2);
  ushort* aggb  = (ushort*)take((size_t)NN * FDIM * 2);
  float* bufD   = (float*)take((size_t)NN * CC * 4);
  ushort* Wt[3];
  for (int i = 0; i < 3; i++) Wt[i] = (ushort*)take((size_t)256 * 256 * 2);
  float* s_arr  = (float*)take((size_t)NN * HH * 4);
  float* d_arr  = (float*)take((size_t)NN * HH * 4);
  // zero-region: deg + 3 per-layer stat buffers (colsum|colsumsq each) -> ONE memset
  char* zbase   = (char*)take(0);
  int* deg      = (int*)take((size_t)NN * 4);
  float* cs[3];
  for (int i = 0; i < 3; i++) cs[i] = (float*)take(2048);   // [0:256)=colsum, [256:512)=colsumsq
  size_t zlen   = (size_t)(((char*)cs[2] + 2048) - zbase);
  int* cursor   = (int*)take((size_t)NN * 4);
  int* rowptr   = (int*)take((size_t)(NN + 1) * 4);
  int* csr_src  = (int*)take((size_t)ET * 4);
  int* bsum     = (int*)take(512);
  int* boff     = (int*)take(512);

  hipMemsetAsync(zbase, 0, zlen, stream);   // deg + all 3 layers' norm stats

  // CSR build (reused by all 3 layers)
  degree_kernel<<<(ET + 255) / 256, 256, 0, stream>>>(ei, is64, deg);
  scan1_kernel<<<SCAN_NB, SCAN_BLK, 0, stream>>>(deg, rowptr, bsum);
  scan2_kernel<<<1, 128, 0, stream>>>(bsum, boff, rowptr);
  scan3_kernel<<<SCAN_NB, SCAN_BLK, 0, stream>>>(rowptr, cursor, boff);
  fill_kernel<<<(ET + 255) / 256, 256, 0, stream>>>(ei, is64, cursor, csr_src);

  // weight prep (x is consumed in f32 directly by layer-0 gemm)
  conv_w_kernel<<<dim3(256, 3), 256, 0, stream>>>(W[0], W[1], W[2], Wt[0], Wt[1], Wt[2]);

  int ggrid = (NN + 31) / 32;   // 1563
  for (int L = 0; L < 3; L++) {
    if (L == 0)
      gemm_bf16<0><<<ggrid, 256, 0, stream>>>((const void*)x, Wt[0], hb,
                                              as_[0], ad_[0], s_arr, d_arr,
                                              nullptr, nullptr, nullptr, nullptr, nullptr);
    else
      gemm_bf16<1><<<ggrid, 256, 0, stream>>>((const void*)aggb, Wt[L], hb,
                                              as_[L], ad_[L], s_arr, d_arr,
                                              cs[L - 1], cs[L - 1] + 256,
                                              ga[L - 1], gw[L - 1], gb[L - 1]);
    if (L < 2) {
      agg_kernel<true><<<NN / 4, 256, 0, stream>>>(hb, s_arr, d_arr, rowptr, csr_src, b_[L], aggb);
      norm_reduce_bf<<<(NN + 127) / 128, 256, 0, stream>>>(aggb, cs[L], cs[L] + 256);
    } else {
      agg_kernel<false><<<NN / 4, 256, 0, stream>>>(hb, s_arr, d_arr, rowptr, csr_src, b_[L], bufD);
      norm_reduce_f32<<<(NN + 127) / 128, 256, 0, stream>>>(bufD, cs[2], cs[2] + 256);
    }
  }
  mlp_kernel<<<(NN + 255) / 256, 256, 0, stream>>>(bufD, cs[2], cs[2] + 256,
                                                   ga[2], gw[2], gb[2],
                                                   mW0, mb0, mW1, mb1, mW2, mb2, out);
}

// Round 7
// 692.340 us; speedup vs baseline: 1.0575x; 1.0556x over previous
//
#include <hip/hip_runtime.h>

#define NN 50000
#define EE 800000
#define ET 850000   // EE + NN self loops
#define HH 4
#define CC 64
#define FDIM 256    // HH*CC

#define SCAN_BLK 512
#define SCAN_NB ((NN + SCAN_BLK - 1) / SCAN_BLK)   // 98

typedef unsigned short ushort;
typedef __bf16 bf16x8 __attribute__((ext_vector_type(8)));
typedef float floatx4 __attribute__((ext_vector_type(4)));
typedef ushort ushort8v __attribute__((ext_vector_type(8)));
struct ushort4s { ushort x, y, z, w; };

__device__ __forceinline__ ushort f2bf(float f) {
  union { float f; unsigned u; } v; v.f = f;
  unsigned r = v.u + 0x7fffu + ((v.u >> 16) & 1u);  // RNE
  return (ushort)(r >> 16);
}
__device__ __forceinline__ float bf2f(ushort u) {
  return __uint_as_float(((unsigned)u) << 16);
}

// async global->LDS, 16B per lane. No dest VGPR => scheduler cannot re-serialize
// the prefetch (R6 lesson: register pipelines get undone by the pressure
// minimizer; global_load_lds issues in program order).
__device__ __forceinline__ void gload16(const void* gsrc, void* ldst) {
  __builtin_amdgcn_global_load_lds(
      (const __attribute__((address_space(1))) void*)gsrc,
      (__attribute__((address_space(3))) void*)ldst, 16, 0, 0);
}

// ---------- edge-index dtype handling (is64 decided HOST-side from in_sizes) ----------
__device__ __forceinline__ int get_edge(const void* p, int is64, long long idx) {
  if (is64) return (int)((const long long*)p)[idx];
  return ((const int*)p)[idx];
}

// ---------- CSR build over dst ----------
__global__ void degree_kernel(const void* eidx, int is64, int* deg) {
  int k = blockIdx.x * blockDim.x + threadIdx.x;
  if (k >= ET) return;
  int dst = (k < EE) ? get_edge(eidx, is64, (long long)EE + k) : (k - EE);
  atomicAdd(&deg[dst], 1);
}

__global__ __launch_bounds__(SCAN_BLK) void scan1_kernel(const int* __restrict__ deg,
                                                         int* __restrict__ rowptr,
                                                         int* __restrict__ bsum) {
  __shared__ int sm[SCAN_BLK];
  int t = threadIdx.x;
  int i = blockIdx.x * SCAN_BLK + t;
  int v = (i < NN) ? deg[i] : 0;
  sm[t] = v;
  __syncthreads();
#pragma unroll
  for (int o = 1; o < SCAN_BLK; o <<= 1) {
    int u = (t >= o) ? sm[t - o] : 0;
    __syncthreads();
    sm[t] += u;
    __syncthreads();
  }
  if (i < NN) rowptr[i] = sm[t] - v;                 // local exclusive
  if (t == SCAN_BLK - 1) bsum[blockIdx.x] = sm[t];   // block total
}

__global__ __launch_bounds__(128) void scan2_kernel(const int* __restrict__ bsum,
                                                    int* __restrict__ boff,
                                                    int* __restrict__ rowptr) {
  __shared__ int sm[128];
  int t = threadIdx.x;
  int v = (t < SCAN_NB) ? bsum[t] : 0;
  sm[t] = v;
  __syncthreads();
#pragma unroll
  for (int o = 1; o < 128; o <<= 1) {
    int u = (t >= o) ? sm[t - o] : 0;
    __syncthreads();
    sm[t] += u;
    __syncthreads();
  }
  if (t < SCAN_NB) boff[t] = sm[t] - v;  // exclusive block offset
  if (t == 0) rowptr[NN] = ET;
}

__global__ __launch_bounds__(SCAN_BLK) void scan3_kernel(int* __restrict__ rowptr,
                                                         int* __restrict__ cursor,
                                                         const int* __restrict__ boff) {
  int i = blockIdx.x * SCAN_BLK + threadIdx.x;
  if (i >= NN) return;
  int v = rowptr[i] + boff[blockIdx.x];
  rowptr[i] = v;
  cursor[i] = v;
}

__global__ void fill_kernel(const void* eidx, int is64, int* cursor, int* csr_src) {
  int k = blockIdx.x * blockDim.x + threadIdx.x;
  if (k >= ET) return;
  int src, dst;
  if (k < EE) {
    src = get_edge(eidx, is64, k);
    dst = get_edge(eidx, is64, (long long)EE + k);
  } else {
    src = dst = k - EE;
  }
  int pos = atomicAdd(&cursor[dst], 1);
  csr_src[pos] = src;
}

// all three weight transposes in one dispatch (grid.y selects the matrix)
__global__ void conv_w_kernel(const float* __restrict__ W0, const float* __restrict__ W1,
                              const float* __restrict__ W2,
                              ushort* __restrict__ T0, ushort* __restrict__ T1,
                              ushort* __restrict__ T2) {
  const float* W = (blockIdx.y == 0) ? W0 : (blockIdx.y == 1) ? W1 : W2;
  ushort* Wt = (blockIdx.y == 0) ? T0 : (blockIdx.y == 1) ? T1 : T2;
  int idx = blockIdx.x * 256 + threadIdx.x;  // 65536
  int k = idx >> 8, n = idx & 255;
  Wt[n * 256 + k] = f2bf(W[idx]);  // transpose: Wt[n][k]
}

// x f32 -> bf16 once (uniformizes all 3 gemms to bf16 A; halves layer-0 A bytes)
__global__ __launch_bounds__(256) void cvt_x_kernel(const float* __restrict__ x,
                                                    ushort* __restrict__ xb) {
  int i = blockIdx.x * 256 + threadIdx.x;  // 1.6M threads x 8 elems
  const float4* p = (const float4*)x + (size_t)i * 2;
  float4 a = p[0], b = p[1];
  ushort8v o{f2bf(a.x), f2bf(a.y), f2bf(a.z), f2bf(a.w),
             f2bf(b.x), f2bf(b.y), f2bf(b.z), f2bf(b.w)};
  *(ushort8v*)(xb + (size_t)i * 8) = o;
}

// ---------- bf16 MFMA GEMM: m97-lite — global_load_lds dbuf, 1 barrier/k-step (R7) ----------
// R6 lesson: register prefetch is un-expressible (scheduler re-sinks loads, VGPR
// stayed 52, MfmaUtil 3.6%). global_load_lds has NO dest VGPR -> prefetch of
// step s+1 is issued right after the barrier and flies under step s's
// ds_read+MFMA; it only must land by the NEXT barrier. One barrier per step.
// Block 64 rows x 128 cols (R2 geometry), 4 waves, wave tile 32x64 (2x4 16x16).
// LDS 26KB (As 2x4KB + Bs 2x8KB + stats 2KB) -> 6 blocks/CU.
// MODE 0: plain bf16 A (layer 0 reads pre-converted xbf).
// MODE 1: GraphNorm+LeakyReLU applied at LDS->reg frag read (same math/rounding
// as before: y = leaky(fmaf(sc, bf2f(raw), sh)); f2bf(y) -> identical bits).
template <int MODE>
__global__ __launch_bounds__(256) void gemm_bf16(const ushort* __restrict__ Abf,
                                                 const ushort* __restrict__ Bt,
                                                 ushort* __restrict__ C,
                                                 const float* __restrict__ as_,
                                                 const float* __restrict__ ad_,
                                                 float* __restrict__ s_arr,
                                                 float* __restrict__ d_arr,
                                                 const float* __restrict__ colsum,
                                                 const float* __restrict__ colsumsq,
                                                 const float* __restrict__ ga,
                                                 const float* __restrict__ gw,
                                                 const float* __restrict__ gb) {
  __shared__ ushort As[2][4][512];   // [buf][row subtile][lane*8]
  __shared__ ushort Bs[2][8][512];   // [buf][col subtile][lane*8]
  __shared__ float scs[FDIM], shs[FDIM];
  int tid = threadIdx.x, w = tid >> 6, l = tid & 63;
  int brow0 = blockIdx.x * 64, bcol0 = blockIdx.y * 128;
  int lm = l & 15, lk = (l >> 4) * 8;
  // staging: wave w stages A subtile w and B subtiles 2w, 2w+1
  int arow = min(brow0 + w * 16 + lm, NN - 1);
  const ushort* ag  = Abf + (size_t)arow * 256 + lk;
  const ushort* bg0 = Bt + (size_t)(bcol0 + (2 * w) * 16 + lm) * 256 + lk;
  const ushort* bg1 = Bt + (size_t)(bcol0 + (2 * w + 1) * 16 + lm) * 256 + lk;
  ushort* lA  = &As[0][w][l * 8];
  ushort* lB0 = &Bs[0][2 * w][l * 8];
  ushort* lB1 = &Bs[0][2 * w + 1][l * 8];

  if constexpr (MODE == 1) {
    const float invn = 1.0f / (float)NN;
    float mu = colsum[tid] * invn;
    float ex2 = colsumsq[tid] * invn;
    float a = ga[tid];
    float var = fmaxf(ex2 - (2.f * a - a * a) * mu * mu, 0.f);
    float s = gw[tid] * rsqrtf(var + 1e-5f);
    scs[tid] = s;
    shs[tid] = gb[tid] - s * a * mu;
    // no explicit barrier: the loop-top __syncthreads() (s=0) orders this
    // before the first frag read.
  }

  // prologue: stage k0=0 into buf 0
  gload16(ag, lA);
  gload16(bg0, lB0);
  gload16(bg1, lB1);

  floatx4 acc[2][4];
#pragma unroll
  for (int i = 0; i < 2; i++)
#pragma unroll
    for (int j = 0; j < 4; j++) acc[i][j] = floatx4{0.f, 0.f, 0.f, 0.f};

  int wm = (w >> 1) * 2, wn = (w & 1) * 4;

#pragma unroll
  for (int s = 0; s < 8; ++s) {
    int buf = s & 1;
    __syncthreads();   // drains stage(s) (vmcnt) + syncs; stage(s+1) below is NOT drained here
    if (s < 7) {
      int k1 = (s + 1) * 32;
      int ao = (buf ^ 1) * 2048;   // As buf stride in ushorts (4*512)
      int bo = (buf ^ 1) * 4096;   // Bs buf stride (8*512)
      gload16(ag + k1, lA + ao);
      gload16(bg0 + k1, lB0 + bo);
      gload16(bg1 + k1, lB1 + bo);
    }
    bf16x8 af[2], bfr[4];
    if constexpr (MODE == 0) {
#pragma unroll
      for (int i = 0; i < 2; i++) af[i] = *(const bf16x8*)&As[buf][wm + i][l * 8];
    } else {
      int k = s * 32 + lk;
      float4 sc0 = *(const float4*)&scs[k];
      float4 sc1 = *(const float4*)&scs[k + 4];
      float4 sh0 = *(const float4*)&shs[k];
      float4 sh1 = *(const float4*)&shs[k + 4];
#pragma unroll
      for (int i = 0; i < 2; i++) {
        ushort8v r = *(const ushort8v*)&As[buf][wm + i][l * 8];
        ushort8v a;
#pragma unroll
        for (int j = 0; j < 4; j++) {
          float y0 = fmaf(((const float*)&sc0)[j], bf2f(r[j]), ((const float*)&sh0)[j]);
          float y1 = fmaf(((const float*)&sc1)[j], bf2f(r[j + 4]), ((const float*)&sh1)[j]);
          y0 = fmaxf(y0, 0.01f * y0);
          y1 = fmaxf(y1, 0.01f * y1);
          a[j] = f2bf(y0);
          a[j + 4] = f2bf(y1);
        }
        af[i] = *(bf16x8*)&a;
      }
    }
#pragma unroll
    for (int j = 0; j < 4; j++) bfr[j] = *(const bf16x8*)&Bs[buf][wn + j][l * 8];
#pragma unroll
    for (int i = 0; i < 2; i++)
#pragma unroll
      for (int j = 0; j < 4; j++)
        acc[i][j] = __builtin_amdgcn_mfma_f32_16x16x32_bf16(af[i], bfr[j], acc[i][j], 0, 0, 0);
  }

  int quad = l >> 4;
  // ----- C store -----
#pragma unroll
  for (int i = 0; i < 2; i++) {
    int rr0 = brow0 + (wm + i) * 16 + quad * 4;
#pragma unroll
    for (int j = 0; j < 4; j++) {
      int col = bcol0 + (wn + j) * 16 + lm;
#pragma unroll
      for (int r = 0; r < 4; r++) {
        int row = rr0 + r;
        if (row < NN) C[(size_t)row * 256 + col] = f2bf(acc[i][j][r]);
      }
    }
  }
  // ----- s/d epilogue: wave w owns head (bcol0>>6)+(w&1) for its rows -----
  float asv[4], adv[4];
#pragma unroll
  for (int j = 0; j < 4; j++) {
    int col = bcol0 + (wn + j) * 16 + lm;
    asv[j] = as_[col];
    adv[j] = ad_[col];
  }
  int head = (bcol0 >> 6) + (w & 1);
#pragma unroll
  for (int i = 0; i < 2; i++) {
#pragma unroll
    for (int r = 0; r < 4; r++) {
      float sp = acc[i][0][r] * asv[0] + acc[i][1][r] * asv[1] +
                 acc[i][2][r] * asv[2] + acc[i][3][r] * asv[3];
      float dp = acc[i][0][r] * adv[0] + acc[i][1][r] * adv[1] +
                 acc[i][2][r] * adv[2] + acc[i][3][r] * adv[3];
      sp += __shfl_xor(sp, 1); dp += __shfl_xor(dp, 1);
      sp += __shfl_xor(sp, 2); dp += __shfl_xor(dp, 2);
      sp += __shfl_xor(sp, 4); dp += __shfl_xor(dp, 4);
      sp += __shfl_xor(sp, 8); dp += __shfl_xor(dp, 8);
      if (lm == 0) {
        int row = brow0 + (wm + i) * 16 + quad * 4 + r;
        if (row < NN) {
          s_arr[row * HH + head] = sp;
          d_arr[row * HH + head] = dp;
        }
      }
    }
  }
}

// ---------- aggregation: one wave per node; 16-deep gather (R2, proven) ----------
template <bool CONCAT>
__global__ __launch_bounds__(256) void agg_kernel(const ushort* __restrict__ hb,
                                                  const float* __restrict__ s_arr,
                                                  const float* __restrict__ d_arr,
                                                  const int* __restrict__ rowptr,
                                                  const int* __restrict__ csr_src,
                                                  const float* __restrict__ bias,
                                                  void* __restrict__ outp) {
  int w = __builtin_amdgcn_readfirstlane(threadIdx.x >> 6);
  int l = threadIdx.x & 63;
  int head = l >> 4;
  int n = blockIdx.x * 4 + w;
  int beg = rowptr[n], end = rowptr[n + 1];
  float dh = d_arr[n * HH + head];
  float a0 = 0.f, a1 = 0.f, a2 = 0.f, a3 = 0.f, den = 0.f;

  int i = beg;
  // ---- 16-deep main: all loads issued before any consume (max MLP) ----
  for (; i + 16 <= end; i += 16) {
    int ss[16];
#pragma unroll
    for (int t = 0; t < 16; t++) ss[t] = csr_src[i + t];
    float ee[16];
#pragma unroll
    for (int t = 0; t < 16; t++) ee[t] = s_arr[ss[t] * HH + head];
    ushort4s hh[16];
#pragma unroll
    for (int t = 0; t < 16; t++)
      hh[t] = *(const ushort4s*)(hb + (unsigned)(ss[t] * FDIM + l * 4));
#pragma unroll
    for (int t = 0; t < 16; t++) {
      float e = ee[t] + dh;
      e = (e > 0.f) ? e : 0.2f * e;
      float wt = __expf(e);
      den += wt;
      a0 = fmaf(wt, bf2f(hh[t].x), a0);
      a1 = fmaf(wt, bf2f(hh[t].y), a1);
      a2 = fmaf(wt, bf2f(hh[t].z), a2);
      a3 = fmaf(wt, bf2f(hh[t].w), a3);
    }
  }
  // ---- 8-tier ----
  for (; i + 8 <= end; i += 8) {
    int ss[8];
#pragma unroll
    for (int t = 0; t < 8; t++) ss[t] = csr_src[i + t];
    float ee[8];
#pragma unroll
    for (int t = 0; t < 8; t++) ee[t] = s_arr[ss[t] * HH + head];
    ushort4s hh[8];
#pragma unroll
    for (int t = 0; t < 8; t++)
      hh[t] = *(const ushort4s*)(hb + (unsigned)(ss[t] * FDIM + l * 4));
#pragma unroll
    for (int t = 0; t < 8; t++) {
      float e = ee[t] + dh;
      e = (e > 0.f) ? e : 0.2f * e;
      float wt = __expf(e);
      den += wt;
      a0 = fmaf(wt, bf2f(hh[t].x), a0);
      a1 = fmaf(wt, bf2f(hh[t].y), a1);
      a2 = fmaf(wt, bf2f(hh[t].z), a2);
      a3 = fmaf(wt, bf2f(hh[t].w), a3);
    }
  }
  // ---- 4-tier ----
  for (; i + 4 <= end; i += 4) {
    int ss[4];
#pragma unroll
    for (int t = 0; t < 4; t++) ss[t] = csr_src[i + t];
    float ee[4];
#pragma unroll
    for (int t = 0; t < 4; t++) ee[t] = s_arr[ss[t] * HH + head];
    ushort4s hh[4];
#pragma unroll
    for (int t = 0; t < 4; t++)
      hh[t] = *(const ushort4s*)(hb + (unsigned)(ss[t] * FDIM + l * 4));
#pragma unroll
    for (int t = 0; t < 4; t++) {
      float e = ee[t] + dh;
      e = (e > 0.f) ? e : 0.2f * e;
      float wt = __expf(e);
      den += wt;
      a0 = fmaf(wt, bf2f(hh[t].x), a0);
      a1 = fmaf(wt, bf2f(hh[t].y), a1);
      a2 = fmaf(wt, bf2f(hh[t].z), a2);
      a3 = fmaf(wt, bf2f(hh[t].w), a3);
    }
  }
  // ---- scalar tail ----
  for (; i < end; i++) {
    int s0 = csr_src[i];
    float e0 = s_arr[s0 * HH + head] + dh;
    ushort4s h0 = *(const ushort4s*)(hb + (unsigned)(s0 * FDIM + l * 4));
    e0 = (e0 > 0.f) ? e0 : 0.2f * e0;
    float w0 = __expf(e0);
    den += w0;
    a0 = fmaf(w0, bf2f(h0.x), a0); a1 = fmaf(w0, bf2f(h0.y), a1);
    a2 = fmaf(w0, bf2f(h0.z), a2); a3 = fmaf(w0, bf2f(h0.w), a3);
  }
  float inv = 1.0f / den;  // self loop guarantees den > 0
  float r0 = a0 * inv, r1 = a1 * inv, r2 = a2 * inv, r3 = a3 * inv;

  if (CONCAT) {
    float4 bv = ((const float4*)bias)[l];
    ushort4s o;
    o.x = f2bf(r0 + bv.x); o.y = f2bf(r1 + bv.y);
    o.z = f2bf(r2 + bv.z); o.w = f2bf(r3 + bv.w);
    ((ushort4s*)outp)[(unsigned)(n * 64 + l)] = o;
  } else {
    r0 += __shfl_xor(r0, 16); r1 += __shfl_xor(r1, 16);
    r2 += __shfl_xor(r2, 16); r3 += __shfl_xor(r3, 16);
    r0 += __shfl_xor(r0, 32); r1 += __shfl_xor(r1, 32);
    r2 += __shfl_xor(r2, 32); r3 += __shfl_xor(r3, 32);
    if (l < 16) {
      float4 bv = ((const float4*)bias)[l];
      float4 o;
      o.x = 0.25f * r0 + bv.x; o.y = 0.25f * r1 + bv.y;
      o.z = 0.25f * r2 + bv.z; o.w = 0.25f * r3 + bv.w;
      ((float4*)outp)[(unsigned)(n * 16 + l)] = o;
    }
  }
}

// ---------- GraphNorm reduce ----------
__global__ __launch_bounds__(256) void norm_reduce_bf(const ushort* __restrict__ xin,
                                                      float* colsum, float* colsumsq) {
  __shared__ float4 sm1[256], sm2[256];
  int t = threadIdx.x;
  int c4 = (t & 63) * 4;
  int rl = t >> 6;
  int r0 = blockIdx.x * 128;
  int r1 = min(NN, r0 + 128);
  float s0 = 0.f, s1 = 0.f, s2 = 0.f, s3 = 0.f;
  float q0 = 0.f, q1 = 0.f, q2 = 0.f, q3 = 0.f;
  for (int r = r0 + rl; r < r1; r += 4) {
    ushort4s v = *(const ushort4s*)(xin + (size_t)r * FDIM + c4);
    float f0 = bf2f(v.x), f1 = bf2f(v.y), f2 = bf2f(v.z), f3 = bf2f(v.w);
    s0 += f0; q0 += f0 * f0;
    s1 += f1; q1 += f1 * f1;
    s2 += f2; q2 += f2 * f2;
    s3 += f3; q3 += f3 * f3;
  }
  sm1[t] = float4{s0, s1, s2, s3};
  sm2[t] = float4{q0, q1, q2, q3};
  __syncthreads();
  if (t < 64) {
    float4 a = sm1[t], b = sm1[t + 64], c = sm1[t + 128], d = sm1[t + 192];
    atomicAdd(&colsum[c4 + 0], a.x + b.x + c.x + d.x);
    atomicAdd(&colsum[c4 + 1], a.y + b.y + c.y + d.y);
    atomicAdd(&colsum[c4 + 2], a.z + b.z + c.z + d.z);
    atomicAdd(&colsum[c4 + 3], a.w + b.w + c.w + d.w);
    float4 e = sm2[t], f = sm2[t + 64], g = sm2[t + 128], h = sm2[t + 192];
    atomicAdd(&colsumsq[c4 + 0], e.x + f.x + g.x + h.x);
    atomicAdd(&colsumsq[c4 + 1], e.y + f.y + g.y + h.y);
    atomicAdd(&colsumsq[c4 + 2], e.z + f.z + g.z + h.z);
    atomicAdd(&colsumsq[c4 + 3], e.w + f.w + g.w + h.w);
  }
}

__global__ __launch_bounds__(256) void norm_reduce_f32(const float* __restrict__ xin,
                                                       float* colsum, float* colsumsq) {
  int f = threadIdx.x & (CC - 1);
  int rl = threadIdx.x / CC;
  int r0 = blockIdx.x * 128;
  int r1 = min(NN, r0 + 128);
  float s1 = 0.f, s2 = 0.f;
  for (int r = r0 + rl; r < r1; r += 4) {
    float v = xin[(size_t)r * CC + f];
    s1 += v; s2 += v * v;
  }
  atomicAdd(&colsum[f], s1);
  atomicAdd(&colsumsq[f], s2);
}

// ---------- MLP 64->32->16->2 with fused GraphNorm+LeakyReLU on input ----------
__global__ __launch_bounds__(256) void mlp_kernel(const float* __restrict__ xin,
                                                  const float* __restrict__ colsum,
                                                  const float* __restrict__ colsumsq,
                                                  const float* __restrict__ ga,
                                                  const float* __restrict__ gw,
                                                  const float* __restrict__ gb,
                                                  const float* mW0, const float* mb0,
                                                  const float* mW1, const float* mb1,
                                                  const float* mW2, const float* mb2,
                                                  float* __restrict__ out) {
  __shared__ float W0s[64 * 32];
  __shared__ float W1s[32 * 16];
  __shared__ float W2s[16 * 2];
  __shared__ float b0s[32], b1s[16], b2s[2];
  __shared__ float sc[CC], sh[CC];
  int t = threadIdx.x;
  for (int i = t; i < 2048; i += 256) W0s[i] = mW0[i];
  for (int i = t; i < 512; i += 256) W1s[i] = mW1[i];
  if (t < 32) { W2s[t] = mW2[t]; b0s[t] = mb0[t]; }
  if (t < 16) b1s[t] = mb1[t];
  if (t < 2) b2s[t] = mb2[t];
  if (t < CC) {
    const float invn = 1.0f / (float)NN;
    float mu = colsum[t] * invn;
    float ex2 = colsumsq[t] * invn;
    float a = ga[t];
    float var = fmaxf(ex2 - (2.f * a - a * a) * mu * mu, 0.f);
    float s = gw[t] * rsqrtf(var + 1e-5f);
    sc[t] = s; sh[t] = gb[t] - s * a * mu;
  }
  __syncthreads();
  int node = blockIdx.x * 256 + t;
  if (node >= NN) return;
  float in[64];
  const float* xr = xin + (size_t)node * 64;
#pragma unroll
  for (int k = 0; k < 64; k++) {
    float y = sc[k] * xr[k] + sh[k];
    in[k] = (y > 0.f) ? y : 0.01f * y;   // GraphNorm + LeakyReLU(0.01) fused
  }
  float h1[32];
#pragma unroll
  for (int j = 0; j < 32; j++) h1[j] = b0s[j];
#pragma unroll
  for (int k = 0; k < 64; k++) {
    float v = in[k];
#pragma unroll
    for (int j = 0; j < 32; j++) h1[j] += v * W0s[k * 32 + j];
  }
#pragma unroll
  for (int j = 0; j < 32; j++) h1[j] = fmaxf(h1[j], 0.f);
  float h2[16];
#pragma unroll
  for (int j = 0; j < 16; j++) h2[j] = b1s[j];
#pragma unroll
  for (int k = 0; k < 32; k++) {
    float v = h1[k];
#pragma unroll
    for (int j = 0; j < 16; j++) h2[j] += v * W1s[k * 16 + j];
  }
#pragma unroll
  for (int j = 0; j < 16; j++) h2[j] = fmaxf(h2[j], 0.f);
  float o0 = b2s[0], o1 = b2s[1];
#pragma unroll
  for (int k = 0; k < 16; k++) {
    o0 += h2[k] * W2s[k * 2 + 0];
    o1 += h2[k] * W2s[k * 2 + 1];
  }
  out[(size_t)node * 2 + 0] = o0;
  out[(size_t)node * 2 + 1] = o1;
}

extern "C" void kernel_launch(void* const* d_in, const int* in_sizes, int n_in,
                              void* d_out, int out_size, void* d_ws, size_t ws_size,
                              hipStream_t stream) {
  const float* x = (const float*)d_in[0];
  const void* ei = d_in[1];
  const float* W[3]   = {(const float*)d_in[2],  (const float*)d_in[9],  (const float*)d_in[16]};
  const float* as_[3] = {(const float*)d_in[3],  (const float*)d_in[10], (const float*)d_in[17]};
  const float* ad_[3] = {(const float*)d_in[4],  (const float*)d_in[11], (const float*)d_in[18]};
  const float* b_[3]  = {(const float*)d_in[5],  (const float*)d_in[12], (const float*)d_in[19]};
  const float* gw[3]  = {(const float*)d_in[6],  (const float*)d_in[13], (const float*)d_in[20]};
  const float* gb[3]  = {(const float*)d_in[7],  (const float*)d_in[14], (const float*)d_in[21]};
  const float* ga[3]  = {(const float*)d_in[8],  (const float*)d_in[15], (const float*)d_in[22]};
  const float* mW0 = (const float*)d_in[23];
  const float* mb0 = (const float*)d_in[24];
  const float* mW1 = (const float*)d_in[25];
  const float* mb1 = (const float*)d_in[26];
  const float* mW2 = (const float*)d_in[27];
  const float* mb2 = (const float*)d_in[28];
  float* out = (float*)d_out;

  // edge-index dtype from byte size: int64 => 2*EE*8 bytes
  int is64 = (in_sizes[1] == (int)(2u * EE * 8u)) ? 1 : 0;

  char* ws = (char*)d_ws;
  size_t off = 0;
  auto take = [&](size_t bytes) -> char* {
    char* p = ws + off;
    off = (off + bytes + 255) & ~(size_t)255;
    return p;
  };
  ushort* hb    = (ushort*)take((size_t)NN * FDIM * 2);
  ushort* aggb  = (ushort*)take((size_t)NN * FDIM * 2);
  ushort* xbf   = (ushort*)take((size_t)NN * FDIM * 2);
  float* bufD   = (float*)take((size_t)NN * CC * 4);
  ushort* Wt[3];
  for (int i = 0; i < 3; i++) Wt[i] = (ushort*)take((size_t)256 * 256 * 2);
  float* s_arr  = (float*)take((size_t)NN * HH * 4);
  float* d_arr  = (float*)take((size_t)NN * HH * 4);
  // zero-region: deg + 3 per-layer stat buffers (colsum|colsumsq each) -> ONE memset
  char* zbase   = (char*)take(0);
  int* deg      = (int*)take((size_t)NN * 4);
  float* cs[3];
  for (int i = 0; i < 3; i++) cs[i] = (float*)take(2048);   // [0:256)=colsum, [256:512)=colsumsq
  size_t zlen   = (size_t)(((char*)cs[2] + 2048) - zbase);
  int* cursor   = (int*)take((size_t)NN * 4);
  int* rowptr   = (int*)take((size_t)(NN + 1) * 4);
  int* csr_src  = (int*)take((size_t)ET * 4);
  int* bsum     = (int*)take(512);
  int* boff     = (int*)take(512);

  hipMemsetAsync(zbase, 0, zlen, stream);   // deg + all 3 layers' norm stats

  // CSR build (reused by all 3 layers)
  degree_kernel<<<(ET + 255) / 256, 256, 0, stream>>>(ei, is64, deg);
  scan1_kernel<<<SCAN_NB, SCAN_BLK, 0, stream>>>(deg, rowptr, bsum);
  scan2_kernel<<<1, 128, 0, stream>>>(bsum, boff, rowptr);
  scan3_kernel<<<SCAN_NB, SCAN_BLK, 0, stream>>>(rowptr, cursor, boff);
  fill_kernel<<<(ET + 255) / 256, 256, 0, stream>>>(ei, is64, cursor, csr_src);

  // weight prep + x -> bf16
  conv_w_kernel<<<dim3(256, 3), 256, 0, stream>>>(W[0], W[1], W[2], Wt[0], Wt[1], Wt[2]);
  cvt_x_kernel<<<(NN * FDIM / 8 + 255) / 256, 256, 0, stream>>>(x, xbf);

  dim3 ggrid((NN + 63) / 64, 2);   // 782 x 2
  for (int L = 0; L < 3; L++) {
    if (L == 0)
      gemm_bf16<0><<<ggrid, 256, 0, stream>>>(xbf, Wt[0], hb,
                                              as_[0], ad_[0], s_arr, d_arr,
                                              nullptr, nullptr, nullptr, nullptr, nullptr);
    else
      gemm_bf16<1><<<ggrid, 256, 0, stream>>>(aggb, Wt[L], hb,
                                              as_[L], ad_[L], s_arr, d_arr,
                                              cs[L - 1], cs[L - 1] + 256,
                                              ga[L - 1], gw[L - 1], gb[L - 1]);
    if (L < 2) {
      agg_kernel<true><<<NN / 4, 256, 0, stream>>>(hb, s_arr, d_arr, rowptr, csr_src, b_[L], aggb);
      norm_reduce_bf<<<(NN + 127) / 128, 256, 0, stream>>>(aggb, cs[L], cs[L] + 256);
    } else {
      agg_kernel<false><<<NN / 4, 256, 0, stream>>>(hb, s_arr, d_arr, rowptr, csr_src, b_[L], bufD);
      norm_reduce_f32<<<(NN + 127) / 128, 256, 0, stream>>>(bufD, cs[2], cs[2] + 256);
    }
  }
  mlp_kernel<<<(NN + 255) / 256, 256, 0, stream>>>(bufD, cs[2], cs[2] + 256,
                                                   ga[2], gw[2], gb[2],
                                                   mW0, mb0, mW1, mb1, mW2, mb2, out);
}